// Round 11
// baseline (2952.387 us; speedup 1.0000x reference)
//
#include <hip/hip_runtime.h>
#include <hip/hip_bf16.h>
#include <stdint.h>
#include <stddef.h>

// LSTM: T=512, B=64, I=512, H=512.
// Phase 1: xproj GEMM (bf16 MFMA), output re-laid as [t][j=32][row=64][g=4][c=16].
// Phase 2: 128 independent waves (32 col-groups x 4 row-groups), 64-thr WGs.
//   R11 = R10 champion skeleton with the flag handshake replaced by pure
//   tag-in-band (R7/R8 correctness-proven; their perf flaws fixed):
//   - producer: 4 tagged dword stores (bf16 | (t+1)<<16), NO drain, NO flag
//     -> publish path ~0 RT (was drain-ack + flag ~2 RT),
//   - consumer: issue bw+xp (warm-up window), bulk 32x dwordx4 h load, ONE
//     vmcnt(0), single AND-reduce fast path; per-chunk pending-bitmask retry
//     only on miss (16B granularity -- R7's full-slice retry was the storm).
//   Stale tags in buf[t&1] are in {0, t-2} < t, so AND-high == t is exact.
//   Skew self-bounded at 1 step: X's buf[t&1] reads retire before X's t+1
//   publish, which gates any peer's t+2 overwrite of buf[t&1].

#define T_STEPS 512
#define BATCH   64
#define HDIM    512

using short8 = __attribute__((ext_vector_type(8))) short;  // 8 bf16 (4 VGPR) MFMA operand
using f32x4  = __attribute__((ext_vector_type(4))) float;  // MFMA accumulator
using int4v  = __attribute__((ext_vector_type(4))) int;

__device__ __forceinline__ void gload_lds16(const void* g, void* l) {
  __builtin_amdgcn_global_load_lds((const __attribute__((address_space(1))) void*)g,
                                   (__attribute__((address_space(3))) void*)l, 16, 0, 0);
}
__device__ __forceinline__ float sigf(float x) { return 1.0f / (1.0f + __expf(-x)); }
__device__ __forceinline__ float tanh_fast(float x) {
  x = fminf(fmaxf(x, -15.0f), 15.0f);
  float e = __expf(2.0f * x);
  return (e - 1.0f) / (e + 1.0f);
}
__device__ __forceinline__ short bfb(float f) {
  __hip_bfloat16 h = __float2bfloat16(f);
  short s; __builtin_memcpy(&s, &h, 2); return s;
}
__device__ __forceinline__ unsigned bfbits(float f) {
  __hip_bfloat16 h = __float2bfloat16(f);
  unsigned short s; __builtin_memcpy(&s, &h, 2); return (unsigned)s;
}
__device__ __forceinline__ float bf2f(unsigned u) {  // bf16 bits (low 16) -> f32
  return __builtin_bit_cast(float, u << 16);
}

// ---------------- prep: build Wx_bt/Wh_bt [2048][512] bf16, bias[2048], zero hbuf32
__global__ __launch_bounds__(256) void k_prep(
    const float* __restrict__ Wf, const float* __restrict__ bf_,
    const float* __restrict__ Wi, const float* __restrict__ bi,
    const float* __restrict__ Wg, const float* __restrict__ bg,
    const float* __restrict__ Wo, const float* __restrict__ bo,
    __hip_bfloat16* __restrict__ wxbt, __hip_bfloat16* __restrict__ whbt,
    float* __restrict__ bias, unsigned* __restrict__ hbuf32)
{
  int idx = blockIdx.x * 256 + threadIdx.x;   // 4096 blocks -> 1,048,576 = 2048*512
  int row = idx >> 9;                          // 0..2047 (gate-major)
  int k   = idx & 511;
  int g = row >> 9, r = row & 511;
  const float* W = (g == 0) ? Wf : (g == 1) ? Wi : (g == 2) ? Wg : Wo;
  const float* B = (g == 0) ? bf_ : (g == 1) ? bi : (g == 2) ? bg : bo;
  wxbt[(size_t)row * 512 + k] = __float2bfloat16(W[(size_t)r * 1024 + k]);
  whbt[(size_t)row * 512 + k] = __float2bfloat16(W[(size_t)r * 1024 + 512 + k]);
  if (k == 0) bias[row] = B[r];
  if (idx < 2 * BATCH * HDIM) hbuf32[idx] = 0u;   // h=0 (bf16 0), tag=0 (=step 0)
}

// ---------------- convert x to bf16, 8 elems/thread
__global__ __launch_bounds__(256) void k_convx(const float* __restrict__ x,
                                               __hip_bfloat16* __restrict__ xbf)
{
  int idx = blockIdx.x * 256 + threadIdx.x;    // 8192 blocks
  const float4* p = (const float4*)x + (size_t)idx * 2;
  float4 a = p[0], b = p[1];
  short8 o;
  o[0]=bfb(a.x); o[1]=bfb(a.y); o[2]=bfb(a.z); o[3]=bfb(a.w);
  o[4]=bfb(b.x); o[5]=bfb(b.y); o[6]=bfb(b.z); o[7]=bfb(b.w);
  *(short8*)((short*)xbf + (size_t)idx * 8) = o;
}

// ---------------- phase 1 GEMM: [32768,512] x [512 -> 2048] (B^T layout), +bias
// Output re-laid: xproj[t][j][row][g][c]  (t=512, j=32 colgroups, row=64, g=4, c=16)
__global__ __launch_bounds__(256) void k_xproj(
    const __hip_bfloat16* __restrict__ xbf,   // [32768][512]
    const __hip_bfloat16* __restrict__ wxbt,  // [2048][512]
    const float* __restrict__ bias,           // [2048]
    __hip_bfloat16* __restrict__ xproj)       // [512][32][64][4][16]
{
  __shared__ __align__(16) short aT[128 * 64];
  __shared__ __align__(16) short bT[128 * 64];
  const int tid = threadIdx.x, lane = tid & 63, wave = tid >> 6;
  const int m0 = blockIdx.y * 128, n0 = blockIdx.x * 128;
  const int wr = wave >> 1, wc = wave & 1;

  f32x4 acc[4][4] = {};

  for (int s = 0; s < 8; ++s) {               // K=512, BK=64
    __syncthreads();
    const int kbyte = s * 128;
#pragma unroll
    for (int it = 0; it < 4; ++it) {
      int flat = it * 256 + tid;
      int row = flat >> 3, gr = flat & 7;
      int sgr = gr ^ (row & 7);
      const char* ga = (const char*)xbf  + (size_t)(m0 + row) * 1024 + kbyte + sgr * 16;
      const char* gb = (const char*)wxbt + (size_t)(n0 + row) * 1024 + kbyte + sgr * 16;
      gload_lds16(ga, (char*)aT + (it * 256 + wave * 64) * 16);
      gload_lds16(gb, (char*)bT + (it * 256 + wave * 64) * 16);
    }
    __syncthreads();
#pragma unroll
    for (int kk2 = 0; kk2 < 2; ++kk2) {
      short8 af[4], bfr[4];
#pragma unroll
      for (int mt = 0; mt < 4; ++mt) {
        int r = wr * 64 + mt * 16 + (lane & 15);
        int g = (kk2 * 4 + (lane >> 4)) ^ (r & 7);
        af[mt] = *(const short8*)((const char*)aT + r * 128 + g * 16);
      }
#pragma unroll
      for (int nt = 0; nt < 4; ++nt) {
        int r = wc * 64 + nt * 16 + (lane & 15);
        int g = (kk2 * 4 + (lane >> 4)) ^ (r & 7);
        bfr[nt] = *(const short8*)((const char*)bT + r * 128 + g * 16);
      }
#pragma unroll
      for (int mt = 0; mt < 4; ++mt)
#pragma unroll
        for (int nt = 0; nt < 4; ++nt)
          acc[mt][nt] = __builtin_amdgcn_mfma_f32_16x16x32_bf16(af[mt], bfr[nt], acc[mt][nt], 0, 0, 0);
    }
  }
  // epilogue: + bias, store bf16 into re-laid layout. C: col=lane&15, row=(lane>>4)*4+i
#pragma unroll
  for (int nt = 0; nt < 4; ++nt) {
    int n = n0 + wc * 64 + nt * 16 + (lane & 15);
    float bv = bias[n];
    int j2 = (n >> 4) & 31, g2 = n >> 9, c2 = n & 15;
#pragma unroll
    for (int mt = 0; mt < 4; ++mt)
#pragma unroll
      for (int i = 0; i < 4; ++i) {
        int m = m0 + wr * 64 + mt * 16 + (lane >> 4) * 4 + i;
        int tt = m >> 6, rr = m & 63;
        xproj[(((size_t)tt * 32 + j2) * 64 + rr) * 64 + g2 * 16 + c2] =
            __float2bfloat16(acc[mt][nt][i] + bv);
      }
  }
}

// ---------------- phase 2: 128 independent waves (64-thread WGs), no flags.
// Wave bid: j = bid>>2 owns h-cols [j*16,j*16+16); w = bid&3 owns batch rows
// [w*16,w*16+16). hbuf32[2][64][512]: word = bf16(h) | tag<<16.
__global__ __launch_bounds__(64, 1) void k_recur(
    const __hip_bfloat16* __restrict__ xproj, // [512][32][64][4][16]
    const __hip_bfloat16* __restrict__ whbt,  // [2048][512]
    unsigned* __restrict__ hbuf32,            // [2][64][512] tagged words
    float* __restrict__ out)                  // outputs | hx | cx
{
  const int lane = threadIdx.x;
  const int bid  = blockIdx.x;                 // 0..127
  const int j = bid >> 2, w = bid & 3;
  const int hc0 = j * 16, col = lane & 15, q = lane >> 4, mrow = q * 4;

  float c_state[4] = {0.f, 0.f, 0.f, 0.f};
  float* out_hx = out + (size_t)T_STEPS * BATCH * HDIM;
  float* out_cx = out_hx + BATCH * HDIM;

  // invariant base for this wave's Wh slice: B[k][c]=whbt[g*512+hc0+c][k],
  // per lane c=lane&15, k=kk*32+q*8+0..7
  const char* wbase = (const char*)whbt + ((size_t)(hc0 + col)) * 1024 + q * 16;
  // per-lane h chunk base: row = w*16 + (lane&15), words q*8.. (byte q*32)
  const char* hbl = (const char*)hbuf32 +
                    ((size_t)(w * 16 + (lane & 15)) * 512 + q * 8) * 4;

  for (int t = 0; t < T_STEPS; ++t) {
    const int cur = t & 1;
    // ---- bw + xp loads first: their issue/latency is the warm-up window that
    // overlaps producers' store-visibility. Drained by the validation vmcnt(0).
    short8 bw[16][4];
#pragma unroll
    for (int kk = 0; kk < 16; ++kk)
#pragma unroll
      for (int gg = 0; gg < 4; ++gg)
        bw[kk][gg] = *(const short8*)(wbase + (size_t)gg * 524288 + (size_t)kk * 64);

    const char* xpb = (const char*)xproj +
        (((size_t)t * 32 + j) * 4096 + (size_t)(w * 16 + mrow) * 64 + col) * 2;
    unsigned xpu[4][4];
#pragma unroll
    for (int g = 0; g < 4; ++g)
#pragma unroll
      for (int i = 0; i < 4; ++i) {
        const void* p = xpb + i * 128 + g * 32;
        asm volatile("global_load_ushort %0, %1, off"
                     : "=v"(xpu[g][i]) : "v"(p) : "memory");
      }

    // ---- bulk tagged h load + single AND-validate; chunked retry on miss
    const char* hb = hbl + (size_t)cur * (BATCH * HDIM * 4);
    int4v raw[32];
#pragma unroll
    for (int ii = 0; ii < 32; ++ii) {
      const void* p = hb + (size_t)(ii >> 1) * 128 + (ii & 1) * 16;
      asm volatile("global_load_dwordx4 %0, %1, off sc0 sc1"
                   : "=v"(raw[ii]) : "v"(p) : "memory");
    }
    asm volatile("s_waitcnt vmcnt(0)" ::: "memory");
    __builtin_amdgcn_sched_barrier(0);   // rule #18: no tag check above the drain
    unsigned andv = 0xffffffffu;
#pragma unroll
    for (int ii = 0; ii < 32; ++ii)
      andv &= (unsigned)raw[ii][0] & (unsigned)raw[ii][1]
            & (unsigned)raw[ii][2] & (unsigned)raw[ii][3];
    if (__builtin_expect((andv >> 16) != (unsigned)t, 0)) {
      unsigned pend = 0u;
#pragma unroll
      for (int ii = 0; ii < 32; ++ii) {
        unsigned a = (unsigned)raw[ii][0] & (unsigned)raw[ii][1]
                   & (unsigned)raw[ii][2] & (unsigned)raw[ii][3];
        if ((a >> 16) != (unsigned)t) pend |= (1u << ii);
      }
      while (pend) {
#pragma unroll
        for (int ii = 0; ii < 32; ++ii)
          if (pend & (1u << ii)) {
            const void* p = hb + (size_t)(ii >> 1) * 128 + (ii & 1) * 16;
            asm volatile("global_load_dwordx4 %0, %1, off sc0 sc1"
                         : "=v"(raw[ii]) : "v"(p) : "memory");
          }
        asm volatile("s_waitcnt vmcnt(0)" ::: "memory");
        __builtin_amdgcn_sched_barrier(0);
#pragma unroll
        for (int ii = 0; ii < 32; ++ii)
          if (pend & (1u << ii)) {
            unsigned a = (unsigned)raw[ii][0] & (unsigned)raw[ii][1]
                       & (unsigned)raw[ii][2] & (unsigned)raw[ii][3];
            if ((a >> 16) == (unsigned)t) pend &= ~(1u << ii);
          }
      }
    }
    __builtin_amdgcn_sched_barrier(0);

    // ---- unpack tagged words -> A fragments; MFMA (all data in regs, no waits)
    f32x4 acc[4] = {};
#pragma unroll
    for (int kk = 0; kk < 16; ++kk) {
      int4v afw;
      afw[0] = (raw[2*kk][0]   & 0xffff) | (raw[2*kk][1]   << 16);
      afw[1] = (raw[2*kk][2]   & 0xffff) | (raw[2*kk][3]   << 16);
      afw[2] = (raw[2*kk+1][0] & 0xffff) | (raw[2*kk+1][1] << 16);
      afw[3] = (raw[2*kk+1][2] & 0xffff) | (raw[2*kk+1][3] << 16);
      short8 af = __builtin_bit_cast(short8, afw);
#pragma unroll
      for (int gg = 0; gg < 4; ++gg)
        acc[gg] = __builtin_amdgcn_mfma_f32_16x16x32_bf16(af, bw[kk][gg], acc[gg], 0, 0, 0);
    }

    // ---- epilogue: gates, state update (xpu drained by validation vmcnt(0))
    float hnv[4], cnv[4];
#pragma unroll
    for (int i = 0; i < 4; ++i) {
      float pf = acc[0][i] + bf2f(xpu[0][i]);
      float pi = acc[1][i] + bf2f(xpu[1][i]);
      float pg = acc[2][i] + bf2f(xpu[2][i]);
      float po = acc[3][i] + bf2f(xpu[3][i]);
      float fg = sigf(pf), ig = sigf(pi), gg2 = tanh_fast(pg), og = sigf(po);
      float cn = fg * c_state[i] + ig * gg2;
      c_state[i] = cn;
      cnv[i] = cn;
      hnv[i] = og * tanh_fast(cn);
    }
    // ---- tagged h publish: fire-and-forget (NO drain, NO flag)
    if (t < T_STEPS - 1) {
      char* hnxt = (char*)hbuf32 + (size_t)(cur ^ 1) * (BATCH * HDIM * 4) +
                   ((size_t)(w * 16 + mrow) * 512 + hc0 + col) * 4;
      unsigned tag = ((unsigned)(t + 1)) << 16;
#pragma unroll
      for (int i = 0; i < 4; ++i) {
        unsigned word = bfbits(hnv[i]) | tag;
        void* p = hnxt + (size_t)i * 2048;
        asm volatile("global_store_dword %0, %1, off sc0 sc1"
                     :: "v"(p), "v"(word) : "memory");
      }
    }
    // ---- out stores (plain, L2-ack; drained overlapped with next validation)
    float* outb = out + ((size_t)t * BATCH + w * 16 + mrow) * HDIM + hc0 + col;
#pragma unroll
    for (int i = 0; i < 4; ++i) outb[(size_t)i * HDIM] = hnv[i];
    if (t == T_STEPS - 1) {
#pragma unroll
      for (int i = 0; i < 4; ++i) {
        out_hx[(size_t)(w * 16 + mrow + i) * HDIM + hc0 + col] = hnv[i];
        out_cx[(size_t)(w * 16 + mrow + i) * HDIM + hc0 + col] = cnv[i];
      }
    }
  }
}

extern "C" void kernel_launch(void* const* d_in, const int* in_sizes, int n_in,
                              void* d_out, int out_size, void* d_ws, size_t ws_size,
                              hipStream_t stream) {
  const float* x   = (const float*)d_in[0];
  const float* Wf  = (const float*)d_in[1];
  const float* bf_ = (const float*)d_in[2];
  const float* Wi  = (const float*)d_in[3];
  const float* bi  = (const float*)d_in[4];
  const float* Wg  = (const float*)d_in[5];
  const float* bg  = (const float*)d_in[6];
  const float* Wo  = (const float*)d_in[7];
  const float* bo  = (const float*)d_in[8];

  char* ws = (char*)d_ws;
  __hip_bfloat16* xbf   = (__hip_bfloat16*)(ws);                 // 33,554,432 B
  __hip_bfloat16* wxbt  = (__hip_bfloat16*)(ws + 33554432);      //  2,097,152 B
  __hip_bfloat16* whbt  = (__hip_bfloat16*)(ws + 35651584);      //  2,097,152 B
  float*          bias  = (float*)         (ws + 37748736);      //      8,192 B
  __hip_bfloat16* xproj = (__hip_bfloat16*)(ws + 37756928);      // 134,217,728 B
  unsigned*       hbuf32= (unsigned*)      (ws + 171974656);     //    262,144 B

  k_prep <<<4096, 256, 0, stream>>>(Wf, bf_, Wi, bi, Wg, bg, Wo, bo,
                                    wxbt, whbt, bias, hbuf32);
  k_convx<<<8192, 256, 0, stream>>>(x, xbf);
  k_xproj<<<dim3(16, 256), 256, 0, stream>>>(xbf, wxbt, bias, xproj);
  k_recur<<<128, 64, 0, stream>>>(xproj, whbt, hbuf32, (float*)d_out);
}

// Round 12
// 2291.921 us; speedup vs baseline: 1.2882x; 1.2882x over previous
//
#include <hip/hip_runtime.h>
#include <hip/hip_bf16.h>
#include <stdint.h>
#include <stddef.h>

// LSTM: T=512, B=64, I=512, H=512.
// Phase 1: xproj GEMM (bf16 MFMA), output re-laid as [t][j=32][row=64][g=4][c=16].
// Phase 2: 128 independent waves (32 col-groups x 4 row-groups), 64-thr WGs.
//   R12 = R10 champion skeleton (2-deep pipelined flag poll, counted-vmcnt
//   chunk consume, h-stores->flag->out-stores order) with ONE change: the
//   producer publishes its flag WITHOUT draining the h-stores first (saves
//   ~1 LLC RT/step). Safety: h words are 32-bit tagged (bf16 | (t+1)<<16);
//   the consumer validates each 16B-pair chunk (8 words) interleaved with the
//   counted-vmcnt MFMA consume (wave-uniform __all gate; stale tags in
//   buf[t&1] are {0, t-2} < t, so AND-high == t is exact). Stale chunks ->
//   wave-uniform chunked retry (rare: only the flag-overtakes-stores window).

#define T_STEPS 512
#define BATCH   64
#define HDIM    512

using short8 = __attribute__((ext_vector_type(8))) short;  // 8 bf16 (4 VGPR) MFMA operand
using f32x4  = __attribute__((ext_vector_type(4))) float;  // MFMA accumulator
using int4v  = __attribute__((ext_vector_type(4))) int;

__device__ __forceinline__ void gload_lds16(const void* g, void* l) {
  __builtin_amdgcn_global_load_lds((const __attribute__((address_space(1))) void*)g,
                                   (__attribute__((address_space(3))) void*)l, 16, 0, 0);
}
__device__ __forceinline__ float sigf(float x) { return 1.0f / (1.0f + __expf(-x)); }
__device__ __forceinline__ float tanh_fast(float x) {
  x = fminf(fmaxf(x, -15.0f), 15.0f);
  float e = __expf(2.0f * x);
  return (e - 1.0f) / (e + 1.0f);
}
__device__ __forceinline__ short bfb(float f) {
  __hip_bfloat16 h = __float2bfloat16(f);
  short s; __builtin_memcpy(&s, &h, 2); return s;
}
__device__ __forceinline__ unsigned bfbits(float f) {
  __hip_bfloat16 h = __float2bfloat16(f);
  unsigned short s; __builtin_memcpy(&s, &h, 2); return (unsigned)s;
}
__device__ __forceinline__ float bf2f(unsigned u) {  // bf16 bits (low 16) -> f32
  return __builtin_bit_cast(float, u << 16);
}
__device__ __forceinline__ short8 unpack_pair(int4v r0, int4v r1) {
  int4v afw;
  afw[0] = (r0[0] & 0xffff) | (r0[1] << 16);
  afw[1] = (r0[2] & 0xffff) | (r0[3] << 16);
  afw[2] = (r1[0] & 0xffff) | (r1[1] << 16);
  afw[3] = (r1[2] & 0xffff) | (r1[3] << 16);
  return __builtin_bit_cast(short8, afw);
}

// ---------------- prep: build Wx_bt/Wh_bt [2048][512] bf16, bias[2048], zero hbuf32+flags
__global__ __launch_bounds__(256) void k_prep(
    const float* __restrict__ Wf, const float* __restrict__ bf_,
    const float* __restrict__ Wi, const float* __restrict__ bi,
    const float* __restrict__ Wg, const float* __restrict__ bg,
    const float* __restrict__ Wo, const float* __restrict__ bo,
    __hip_bfloat16* __restrict__ wxbt, __hip_bfloat16* __restrict__ whbt,
    float* __restrict__ bias, unsigned* __restrict__ hbuf32, int* __restrict__ flags)
{
  int idx = blockIdx.x * 256 + threadIdx.x;   // 4096 blocks -> 1,048,576 = 2048*512
  int row = idx >> 9;                          // 0..2047 (gate-major)
  int k   = idx & 511;
  int g = row >> 9, r = row & 511;
  const float* W = (g == 0) ? Wf : (g == 1) ? Wi : (g == 2) ? Wg : Wo;
  const float* B = (g == 0) ? bf_ : (g == 1) ? bi : (g == 2) ? bg : bo;
  wxbt[(size_t)row * 512 + k] = __float2bfloat16(W[(size_t)r * 1024 + k]);
  whbt[(size_t)row * 512 + k] = __float2bfloat16(W[(size_t)r * 1024 + 512 + k]);
  if (k == 0) bias[row] = B[r];
  if (idx < 2 * BATCH * HDIM) hbuf32[idx] = 0u;   // h=0 (bf16 0), tag=0 (=step 0)
  if (idx < 128) flags[idx] = 0;
}

// ---------------- convert x to bf16, 8 elems/thread
__global__ __launch_bounds__(256) void k_convx(const float* __restrict__ x,
                                               __hip_bfloat16* __restrict__ xbf)
{
  int idx = blockIdx.x * 256 + threadIdx.x;    // 8192 blocks
  const float4* p = (const float4*)x + (size_t)idx * 2;
  float4 a = p[0], b = p[1];
  short8 o;
  o[0]=bfb(a.x); o[1]=bfb(a.y); o[2]=bfb(a.z); o[3]=bfb(a.w);
  o[4]=bfb(b.x); o[5]=bfb(b.y); o[6]=bfb(b.z); o[7]=bfb(b.w);
  *(short8*)((short*)xbf + (size_t)idx * 8) = o;
}

// ---------------- phase 1 GEMM: [32768,512] x [512 -> 2048] (B^T layout), +bias
// Output re-laid: xproj[t][j][row][g][c]  (t=512, j=32 colgroups, row=64, g=4, c=16)
__global__ __launch_bounds__(256) void k_xproj(
    const __hip_bfloat16* __restrict__ xbf,   // [32768][512]
    const __hip_bfloat16* __restrict__ wxbt,  // [2048][512]
    const float* __restrict__ bias,           // [2048]
    __hip_bfloat16* __restrict__ xproj)       // [512][32][64][4][16]
{
  __shared__ __align__(16) short aT[128 * 64];
  __shared__ __align__(16) short bT[128 * 64];
  const int tid = threadIdx.x, lane = tid & 63, wave = tid >> 6;
  const int m0 = blockIdx.y * 128, n0 = blockIdx.x * 128;
  const int wr = wave >> 1, wc = wave & 1;

  f32x4 acc[4][4] = {};

  for (int s = 0; s < 8; ++s) {               // K=512, BK=64
    __syncthreads();
    const int kbyte = s * 128;
#pragma unroll
    for (int it = 0; it < 4; ++it) {
      int flat = it * 256 + tid;
      int row = flat >> 3, gr = flat & 7;
      int sgr = gr ^ (row & 7);
      const char* ga = (const char*)xbf  + (size_t)(m0 + row) * 1024 + kbyte + sgr * 16;
      const char* gb = (const char*)wxbt + (size_t)(n0 + row) * 1024 + kbyte + sgr * 16;
      gload_lds16(ga, (char*)aT + (it * 256 + wave * 64) * 16);
      gload_lds16(gb, (char*)bT + (it * 256 + wave * 64) * 16);
    }
    __syncthreads();
#pragma unroll
    for (int kk2 = 0; kk2 < 2; ++kk2) {
      short8 af[4], bfr[4];
#pragma unroll
      for (int mt = 0; mt < 4; ++mt) {
        int r = wr * 64 + mt * 16 + (lane & 15);
        int g = (kk2 * 4 + (lane >> 4)) ^ (r & 7);
        af[mt] = *(const short8*)((const char*)aT + r * 128 + g * 16);
      }
#pragma unroll
      for (int nt = 0; nt < 4; ++nt) {
        int r = wc * 64 + nt * 16 + (lane & 15);
        int g = (kk2 * 4 + (lane >> 4)) ^ (r & 7);
        bfr[nt] = *(const short8*)((const char*)bT + r * 128 + g * 16);
      }
#pragma unroll
      for (int mt = 0; mt < 4; ++mt)
#pragma unroll
        for (int nt = 0; nt < 4; ++nt)
          acc[mt][nt] = __builtin_amdgcn_mfma_f32_16x16x32_bf16(af[mt], bfr[nt], acc[mt][nt], 0, 0, 0);
    }
  }
  // epilogue: + bias, store bf16 into re-laid layout. C: col=lane&15, row=(lane>>4)*4+i
#pragma unroll
  for (int nt = 0; nt < 4; ++nt) {
    int n = n0 + wc * 64 + nt * 16 + (lane & 15);
    float bv = bias[n];
    int j2 = (n >> 4) & 31, g2 = n >> 9, c2 = n & 15;
#pragma unroll
    for (int mt = 0; mt < 4; ++mt)
#pragma unroll
      for (int i = 0; i < 4; ++i) {
        int m = m0 + wr * 64 + mt * 16 + (lane >> 4) * 4 + i;
        int tt = m >> 6, rr = m & 63;
        xproj[(((size_t)tt * 32 + j2) * 64 + rr) * 64 + g2 * 16 + c2] =
            __float2bfloat16(acc[mt][nt][i] + bv);
      }
  }
}

// ---------------- phase 2: 128 independent waves (64-thread WGs).
// Wave bid: j = bid>>2 owns h-cols [j*16,j*16+16); w = bid&3 owns batch rows
// [w*16,w*16+16). flags[w*32+j]; hbuf32[2][64][512] tagged words.
__global__ __launch_bounds__(64, 1) void k_recur(
    const __hip_bfloat16* __restrict__ xproj, // [512][32][64][4][16]
    const __hip_bfloat16* __restrict__ whbt,  // [2048][512]
    unsigned* __restrict__ hbuf32,            // [2][64][512] tagged words
    float* __restrict__ out,                  // outputs | hx | cx
    int* __restrict__ flags)                  // [128], layout w*32+j
{
  const int lane = threadIdx.x;
  const int bid  = blockIdx.x;                 // 0..127
  const int j = bid >> 2, w = bid & 3;
  const int hc0 = j * 16, col = lane & 15, q = lane >> 4, mrow = q * 4;

  float c_state[4] = {0.f, 0.f, 0.f, 0.f};
  float* out_hx = out + (size_t)T_STEPS * BATCH * HDIM;
  float* out_cx = out_hx + BATCH * HDIM;

  // invariant base for this wave's Wh slice: B[k][c]=whbt[g*512+hc0+c][k],
  // per lane c=lane&15, k=kk*32+q*8+0..7
  const char* wbase = (const char*)whbt + ((size_t)(hc0 + col)) * 1024 + q * 16;
  // per-lane h word base: row = w*16 + (lane&15), words q*8.. (byte q*32)
  const char* hbl = (const char*)hbuf32 +
                    ((size_t)(w * 16 + (lane & 15)) * 512 + q * 8) * 4;

  for (int t = 0; t < T_STEPS; ++t) {
    const int cur = t & 1;
    // ---- Wh slice loads: plain, L2-hot, issued BEFORE the poll so they fly
    // during the spin. "memory" clobbers below pin them here.
    short8 bw[16][4];
#pragma unroll
    for (int kk = 0; kk < 16; ++kk)
#pragma unroll
      for (int gg = 0; gg < 4; ++gg)
        bw[kk][gg] = *(const short8*)(wbase + (size_t)gg * 524288 + (size_t)kk * 64);

    // ---- xp loads, also pre-poll (drained by the pre-spin vmcnt(0))
    const char* xpb = (const char*)xproj +
        (((size_t)t * 32 + j) * 4096 + (size_t)(w * 16 + mrow) * 64 + col) * 2;
    unsigned xpu[4][4];
#pragma unroll
    for (int g = 0; g < 4; ++g)
#pragma unroll
      for (int i = 0; i < 4; ++i) {
        const void* p = xpb + i * 128 + g * 32;
        asm volatile("global_load_ushort %0, %1, off"
                     : "=v"(xpu[g][i]) : "v"(p) : "memory");
      }
    // ---- 2-deep pipelined poll of own row-group's 32 flags (R10-proven).
    if (t > 0) {
      const int* fp = flags + w * 32 + (lane & 31);
      int f0, f1;
      asm volatile("global_load_dword %0, %1, off sc0 sc1" : "=v"(f0) : "v"(fp) : "memory");
      asm volatile("s_waitcnt vmcnt(0)" ::: "memory");
      if (f0 < t) {
        for (;;) {
          asm volatile("global_load_dword %0, %1, off sc0 sc1" : "=v"(f1) : "v"(fp) : "memory");
          asm volatile("s_waitcnt vmcnt(1)" ::: "memory");   // f0 complete
          if (f0 >= t) break;                                 // f1 still flying
          asm volatile("global_load_dword %0, %1, off sc0 sc1" : "=v"(f0) : "v"(fp) : "memory");
          asm volatile("s_waitcnt vmcnt(1)" ::: "memory");   // f1 complete
          if (f1 >= t) break;                                 // f0 still flying
        }
        asm volatile("s_waitcnt vmcnt(0)" ::: "memory");      // retire leftover poll
      }
    } else {
      asm volatile("s_waitcnt vmcnt(0)" ::: "memory");        // t=0: drain bw/xp
    }

    // ---- issue all 32 tagged h loads; consume per kk with counted vmcnt +
    // inline tag validation (wave-uniform) + 4 MFMAs.
    const char* hb = hbl + (size_t)cur * (BATCH * HDIM * 4);
    int4v raw[32];
#pragma unroll
    for (int ii = 0; ii < 32; ++ii) {
      const void* p = hb + (size_t)(ii >> 1) * 128 + (ii & 1) * 16;
      asm volatile("global_load_dwordx4 %0, %1, off sc0 sc1"
                   : "=v"(raw[ii]) : "v"(p) : "memory");
    }
    f32x4 acc[4] = {};
    unsigned bad = 0u;
#pragma unroll
    for (int kk = 0; kk < 16; ++kk) {
      asm volatile("s_waitcnt vmcnt(%0)" :: "i"(30 - 2 * kk) : "memory");
      __builtin_amdgcn_sched_barrier(0);   // rule #18: checks/MFMA below the wait
      unsigned a = (unsigned)raw[2*kk][0]   & (unsigned)raw[2*kk][1]
                 & (unsigned)raw[2*kk][2]   & (unsigned)raw[2*kk][3]
                 & (unsigned)raw[2*kk+1][0] & (unsigned)raw[2*kk+1][1]
                 & (unsigned)raw[2*kk+1][2] & (unsigned)raw[2*kk+1][3];
      if (__builtin_expect(__all((a >> 16) == (unsigned)t), 1)) {
        short8 af = unpack_pair(raw[2*kk], raw[2*kk+1]);
#pragma unroll
        for (int gg = 0; gg < 4; ++gg)
          acc[gg] = __builtin_amdgcn_mfma_f32_16x16x32_bf16(af, bw[kk][gg], acc[gg], 0, 0, 0);
      } else {
        bad |= 1u << kk;                   // wave-uniform (set under !__all)
      }
    }
    if (__builtin_expect(bad != 0u, 0)) {  // rare: flag overtook h-stores
      while (bad) {
        unsigned still = 0u;
#pragma unroll
        for (int kk = 0; kk < 16; ++kk)
          if (bad & (1u << kk)) {
            const void* p0 = hb + (size_t)kk * 256;
            const void* p1 = hb + (size_t)kk * 256 + 16;
            asm volatile("global_load_dwordx4 %0, %1, off sc0 sc1"
                         : "=v"(raw[2*kk]) : "v"(p0) : "memory");
            asm volatile("global_load_dwordx4 %0, %1, off sc0 sc1"
                         : "=v"(raw[2*kk+1]) : "v"(p1) : "memory");
          }
        asm volatile("s_waitcnt vmcnt(0)" ::: "memory");
        __builtin_amdgcn_sched_barrier(0);
#pragma unroll
        for (int kk = 0; kk < 16; ++kk)
          if (bad & (1u << kk)) {
            unsigned a = (unsigned)raw[2*kk][0]   & (unsigned)raw[2*kk][1]
                       & (unsigned)raw[2*kk][2]   & (unsigned)raw[2*kk][3]
                       & (unsigned)raw[2*kk+1][0] & (unsigned)raw[2*kk+1][1]
                       & (unsigned)raw[2*kk+1][2] & (unsigned)raw[2*kk+1][3];
            if (__all((a >> 16) == (unsigned)t)) {
              short8 af = unpack_pair(raw[2*kk], raw[2*kk+1]);
#pragma unroll
              for (int gg = 0; gg < 4; ++gg)
                acc[gg] = __builtin_amdgcn_mfma_f32_16x16x32_bf16(af, bw[kk][gg], acc[gg], 0, 0, 0);
            } else {
              still |= 1u << kk;
            }
          }
        bad = still;
      }
    }

    // ---- epilogue: gates, state update (xpu drained pre-spin / by h waits)
    float hnv[4], cnv[4];
#pragma unroll
    for (int i = 0; i < 4; ++i) {
      float pf = acc[0][i] + bf2f(xpu[0][i]);
      float pi = acc[1][i] + bf2f(xpu[1][i]);
      float pg = acc[2][i] + bf2f(xpu[2][i]);
      float po = acc[3][i] + bf2f(xpu[3][i]);
      float fg = sigf(pf), ig = sigf(pi), gg2 = tanh_fast(pg), og = sigf(po);
      float cn = fg * c_state[i] + ig * gg2;
      c_state[i] = cn;
      cnv[i] = cn;
      hnv[i] = og * tanh_fast(cn);
    }
    // ---- tagged h stores, then flag: NO drain between (tags validate);
    // out stores AFTER the flag (off the publish path).
    if (t < T_STEPS - 1) {
      char* hnxt = (char*)hbuf32 + (size_t)(cur ^ 1) * (BATCH * HDIM * 4) +
                   ((size_t)(w * 16 + mrow) * 512 + hc0 + col) * 4;
      unsigned tag = ((unsigned)(t + 1)) << 16;
#pragma unroll
      for (int i = 0; i < 4; ++i) {
        unsigned word = bfbits(hnv[i]) | tag;
        void* p = hnxt + (size_t)i * 2048;
        asm volatile("global_store_dword %0, %1, off sc0 sc1"
                     :: "v"(p), "v"(word) : "memory");
      }
      if (lane == 0) {
        int nv = t + 1;
        int* fp2 = flags + w * 32 + j;
        asm volatile("global_store_dword %0, %1, off sc0 sc1"
                     :: "v"(fp2), "v"(nv) : "memory");
      }
    }
    float* outb = out + ((size_t)t * BATCH + w * 16 + mrow) * HDIM + hc0 + col;
#pragma unroll
    for (int i = 0; i < 4; ++i) outb[(size_t)i * HDIM] = hnv[i];
    if (t == T_STEPS - 1) {
#pragma unroll
      for (int i = 0; i < 4; ++i) {
        out_hx[(size_t)(w * 16 + mrow + i) * HDIM + hc0 + col] = hnv[i];
        out_cx[(size_t)(w * 16 + mrow + i) * HDIM + hc0 + col] = cnv[i];
      }
    }
  }
}

extern "C" void kernel_launch(void* const* d_in, const int* in_sizes, int n_in,
                              void* d_out, int out_size, void* d_ws, size_t ws_size,
                              hipStream_t stream) {
  const float* x   = (const float*)d_in[0];
  const float* Wf  = (const float*)d_in[1];
  const float* bf_ = (const float*)d_in[2];
  const float* Wi  = (const float*)d_in[3];
  const float* bi  = (const float*)d_in[4];
  const float* Wg  = (const float*)d_in[5];
  const float* bg  = (const float*)d_in[6];
  const float* Wo  = (const float*)d_in[7];
  const float* bo  = (const float*)d_in[8];

  char* ws = (char*)d_ws;
  __hip_bfloat16* xbf   = (__hip_bfloat16*)(ws);                 // 33,554,432 B
  __hip_bfloat16* wxbt  = (__hip_bfloat16*)(ws + 33554432);      //  2,097,152 B
  __hip_bfloat16* whbt  = (__hip_bfloat16*)(ws + 35651584);      //  2,097,152 B
  float*          bias  = (float*)         (ws + 37748736);      //      8,192 B
  __hip_bfloat16* xproj = (__hip_bfloat16*)(ws + 37756928);      // 134,217,728 B
  unsigned*       hbuf32= (unsigned*)      (ws + 171974656);     //    262,144 B
  int*            flags = (int*)           (ws + 172236800);     //        512 B

  k_prep <<<4096, 256, 0, stream>>>(Wf, bf_, Wi, bi, Wg, bg, Wo, bo,
                                    wxbt, whbt, bias, hbuf32, flags);
  k_convx<<<8192, 256, 0, stream>>>(x, xbf);
  k_xproj<<<dim3(16, 256), 256, 0, stream>>>(xbf, wxbt, bias, xproj);
  k_recur<<<128, 64, 0, stream>>>(xproj, whbt, hbuf32, (float*)d_out, flags);
}

// Round 13
// 1974.010 us; speedup vs baseline: 1.4956x; 1.1610x over previous
//
#include <hip/hip_runtime.h>
#include <hip/hip_bf16.h>
#include <stdint.h>
#include <stddef.h>

// LSTM: T=512, B=64, I=512, H=512.
// Phase 1: xproj GEMM (bf16 MFMA), output in CONSUMER layout:
//   xproj2[t][j][w][q][c][g*4+i] -- each recurrent lane reads its 16 gate
//   pre-activations as 2 contiguous dwordx4 (32 B).
// Phase 2: 32 WGs x 256 threads (4 waves). WG b: w = b&3 (batch rows
//   w*16..+15), waves are j = (b>>2)*4 + wave. R13 over R10 champion:
//   - only wave 0 polls the group's 32 flags (2-deep pipelined, R10-proven);
//     barrier releases the other 3 waves (poll LLC traffic / 4),
//   - cooperative h load: each wave pulls 4 of 16 chunks (sc0 sc1) ->
//     XOR-swizzled LDS tile (granule ^= row&7; 2-way max on ds_read_b128);
//     h LLC read traffic / 4 (was 32 waves x same 16 KB),
//   - producer publish unchanged: h-stores -> vmcnt(0) -> flag -> out stores.

#define T_STEPS 512
#define BATCH   64
#define HDIM    512

using short8 = __attribute__((ext_vector_type(8))) short;  // 8 bf16 (4 VGPR) MFMA operand
using f32x4  = __attribute__((ext_vector_type(4))) float;  // MFMA accumulator
using int4v  = __attribute__((ext_vector_type(4))) int;

__device__ __forceinline__ void gload_lds16(const void* g, void* l) {
  __builtin_amdgcn_global_load_lds((const __attribute__((address_space(1))) void*)g,
                                   (__attribute__((address_space(3))) void*)l, 16, 0, 0);
}
__device__ __forceinline__ float sigf(float x) { return 1.0f / (1.0f + __expf(-x)); }
__device__ __forceinline__ float tanh_fast(float x) {
  x = fminf(fmaxf(x, -15.0f), 15.0f);
  float e = __expf(2.0f * x);
  return (e - 1.0f) / (e + 1.0f);
}
__device__ __forceinline__ short bfb(float f) {
  __hip_bfloat16 h = __float2bfloat16(f);
  short s; __builtin_memcpy(&s, &h, 2); return s;
}
__device__ __forceinline__ unsigned bfbits(float f) {
  __hip_bfloat16 h = __float2bfloat16(f);
  unsigned short s; __builtin_memcpy(&s, &h, 2); return (unsigned)s;
}
__device__ __forceinline__ float bf2f(unsigned u) {  // bf16 bits (low 16) -> f32
  return __builtin_bit_cast(float, u << 16);
}

// ---------------- prep: build Wx_bt/Wh_bt [2048][512] bf16, bias[2048], zero hbuf+flags
__global__ __launch_bounds__(256) void k_prep(
    const float* __restrict__ Wf, const float* __restrict__ bf_,
    const float* __restrict__ Wi, const float* __restrict__ bi,
    const float* __restrict__ Wg, const float* __restrict__ bg,
    const float* __restrict__ Wo, const float* __restrict__ bo,
    __hip_bfloat16* __restrict__ wxbt, __hip_bfloat16* __restrict__ whbt,
    float* __restrict__ bias, __hip_bfloat16* __restrict__ hbuf, int* __restrict__ flags)
{
  int idx = blockIdx.x * 256 + threadIdx.x;   // 4096 blocks -> 1,048,576 = 2048*512
  int row = idx >> 9;                          // 0..2047 (gate-major)
  int k   = idx & 511;
  int g = row >> 9, r = row & 511;
  const float* W = (g == 0) ? Wf : (g == 1) ? Wi : (g == 2) ? Wg : Wo;
  const float* B = (g == 0) ? bf_ : (g == 1) ? bi : (g == 2) ? bg : bo;
  wxbt[(size_t)row * 512 + k] = __float2bfloat16(W[(size_t)r * 1024 + k]);
  whbt[(size_t)row * 512 + k] = __float2bfloat16(W[(size_t)r * 1024 + 512 + k]);
  if (k == 0) bias[row] = B[r];
  if (idx < 2 * BATCH * HDIM) hbuf[idx] = __float2bfloat16(0.0f);  // both h buffers
  if (idx < 128) flags[idx] = 0;
}

// ---------------- convert x to bf16, 8 elems/thread
__global__ __launch_bounds__(256) void k_convx(const float* __restrict__ x,
                                               __hip_bfloat16* __restrict__ xbf)
{
  int idx = blockIdx.x * 256 + threadIdx.x;    // 8192 blocks
  const float4* p = (const float4*)x + (size_t)idx * 2;
  float4 a = p[0], b = p[1];
  short8 o;
  o[0]=bfb(a.x); o[1]=bfb(a.y); o[2]=bfb(a.z); o[3]=bfb(a.w);
  o[4]=bfb(b.x); o[5]=bfb(b.y); o[6]=bfb(b.z); o[7]=bfb(b.w);
  *(short8*)((short*)xbf + (size_t)idx * 8) = o;
}

// ---------------- phase 1 GEMM: [32768,512] x [512 -> 2048] (B^T layout), +bias
// Output layout: xproj2 elem index = ((((t*32+j)*4+w)*4+q)*16+c)*16 + g*4+i
__global__ __launch_bounds__(256) void k_xproj(
    const __hip_bfloat16* __restrict__ xbf,   // [32768][512]
    const __hip_bfloat16* __restrict__ wxbt,  // [2048][512]
    const float* __restrict__ bias,           // [2048]
    __hip_bfloat16* __restrict__ xproj)       // consumer layout, 2048*32768 elems
{
  __shared__ __align__(16) short aT[128 * 64];
  __shared__ __align__(16) short bT[128 * 64];
  const int tid = threadIdx.x, lane = tid & 63, wave = tid >> 6;
  const int m0 = blockIdx.y * 128, n0 = blockIdx.x * 128;
  const int wr = wave >> 1, wc = wave & 1;

  f32x4 acc[4][4] = {};

  for (int s = 0; s < 8; ++s) {               // K=512, BK=64
    __syncthreads();
    const int kbyte = s * 128;
#pragma unroll
    for (int it = 0; it < 4; ++it) {
      int flat = it * 256 + tid;
      int row = flat >> 3, gr = flat & 7;
      int sgr = gr ^ (row & 7);
      const char* ga = (const char*)xbf  + (size_t)(m0 + row) * 1024 + kbyte + sgr * 16;
      const char* gb = (const char*)wxbt + (size_t)(n0 + row) * 1024 + kbyte + sgr * 16;
      gload_lds16(ga, (char*)aT + (it * 256 + wave * 64) * 16);
      gload_lds16(gb, (char*)bT + (it * 256 + wave * 64) * 16);
    }
    __syncthreads();
#pragma unroll
    for (int kk2 = 0; kk2 < 2; ++kk2) {
      short8 af[4], bfr[4];
#pragma unroll
      for (int mt = 0; mt < 4; ++mt) {
        int r = wr * 64 + mt * 16 + (lane & 15);
        int g = (kk2 * 4 + (lane >> 4)) ^ (r & 7);
        af[mt] = *(const short8*)((const char*)aT + r * 128 + g * 16);
      }
#pragma unroll
      for (int nt = 0; nt < 4; ++nt) {
        int r = wc * 64 + nt * 16 + (lane & 15);
        int g = (kk2 * 4 + (lane >> 4)) ^ (r & 7);
        bfr[nt] = *(const short8*)((const char*)bT + r * 128 + g * 16);
      }
#pragma unroll
      for (int mt = 0; mt < 4; ++mt)
#pragma unroll
        for (int nt = 0; nt < 4; ++nt)
          acc[mt][nt] = __builtin_amdgcn_mfma_f32_16x16x32_bf16(af[mt], bfr[nt], acc[mt][nt], 0, 0, 0);
    }
  }
  // epilogue: + bias, scatter into consumer layout.
#pragma unroll
  for (int nt = 0; nt < 4; ++nt) {
    int n = n0 + wc * 64 + nt * 16 + (lane & 15);
    float bv = bias[n];
    int j2 = (n >> 4) & 31, g2 = n >> 9, c2 = n & 15;
#pragma unroll
    for (int mt = 0; mt < 4; ++mt)
#pragma unroll
      for (int i2 = 0; i2 < 4; ++i2) {
        int m = m0 + wr * 64 + mt * 16 + (lane >> 4) * 4 + i2;
        int tt = m >> 6, rr = m & 63;
        int w2 = rr >> 4, q2 = (rr >> 2) & 3, ii = rr & 3;
        size_t off = ((((size_t)tt * 32 + j2) * 4 + w2) * 4 + q2) * 16 + c2;
        xproj[off * 16 + g2 * 4 + ii] = __float2bfloat16(acc[mt][nt][i2] + bv);
      }
  }
}

// ---------------- phase 2: 32 WGs x 256 threads (4 waves, same w).
// WG b: w = b&3; wave v has j = (b>>2)*4 + v. flags[w*32+j]; hbuf [2][64][512] bf16.
__global__ __launch_bounds__(256, 1) void k_recur(
    const __hip_bfloat16* __restrict__ xproj, // consumer layout
    const __hip_bfloat16* __restrict__ whbt,  // [2048][512]
    __hip_bfloat16* __restrict__ hbuf,        // [2][64][512]
    float* __restrict__ out,                  // outputs | hx | cx
    int* __restrict__ flags)                  // [128], layout w*32+j
{
  __shared__ __align__(16) short hlds[16 * 512];   // 16 KB h tile, XOR-swizzled
  const int tid = threadIdx.x, lane = tid & 63, wave = tid >> 6;
  const int b = blockIdx.x;                    // 0..31
  const int w = b & 3, j = (b >> 2) * 4 + wave;
  const int hc0 = j * 16, col = lane & 15, q = lane >> 4, mrow = q * 4;

  float c_state[4] = {0.f, 0.f, 0.f, 0.f};
  float* out_hx = out + (size_t)T_STEPS * BATCH * HDIM;
  float* out_cx = out_hx + BATCH * HDIM;

  // Wh slice base: B[k][c]=whbt[g*512+hc0+c][k]; per lane c=lane&15, k=kk*32+q*8+..
  const char* wbase = (const char*)whbt + ((size_t)(hc0 + col)) * 1024 + q * 16;
  // coop h-load: wave v pulls granules v*16 + s*4 + q of row (w*16+col)
  // LDS swizzle: byte = row*1024 + (granule ^ (row&7))*16
  const char* lrow = (const char*)hlds + (size_t)col * 1024;
  const int   swz  = col & 7;

  for (int t = 0; t < T_STEPS; ++t) {
    const int cur = t & 1;
    // ---- Wh + xp loads (plain): issued pre-barrier, fly during the spin;
    // pinned here by the asm "memory" clobbers below.
    short8 bw[16][4];
#pragma unroll
    for (int kk = 0; kk < 16; ++kk)
#pragma unroll
      for (int gg = 0; gg < 4; ++gg)
        bw[kk][gg] = *(const short8*)(wbase + (size_t)gg * 524288 + (size_t)kk * 64);

    const char* xpb = (const char*)xproj +
        (((((size_t)t * 32 + j) * 4 + w) * 4 + q) * 16 + col) * 32;
    int4v xw0 = *(const int4v*)xpb;
    int4v xw1 = *(const int4v*)(xpb + 16);

    // ---- wave 0 only: 2-deep pipelined poll of the group's 32 flags
    if (wave == 0 && t > 0) {
      const int* fp = flags + w * 32 + (lane & 31);
      int f0, f1;
      asm volatile("global_load_dword %0, %1, off sc0 sc1" : "=v"(f0) : "v"(fp) : "memory");
      asm volatile("s_waitcnt vmcnt(0)" ::: "memory");
      if (f0 < t) {
        for (;;) {
          asm volatile("global_load_dword %0, %1, off sc0 sc1" : "=v"(f1) : "v"(fp) : "memory");
          asm volatile("s_waitcnt vmcnt(1)" ::: "memory");
          if (f0 >= t) break;
          asm volatile("global_load_dword %0, %1, off sc0 sc1" : "=v"(f0) : "v"(fp) : "memory");
          asm volatile("s_waitcnt vmcnt(1)" ::: "memory");
          if (f1 >= t) break;
        }
        asm volatile("s_waitcnt vmcnt(0)" ::: "memory");
      }
    }
    __syncthreads();   // releases waves 1-3; implicit vmcnt(0) drains bw/xp

    // ---- cooperative h load: 4 chunks per wave (64 B/lane), sc0 sc1
    const char* hgb = (const char*)hbuf + cur * (BATCH * HDIM * 2) +
                      (size_t)(w * 16 + col) * 1024;
    int4v hv[4];
#pragma unroll
    for (int s = 0; s < 4; ++s) {
      const void* p = hgb + (size_t)(wave * 16 + s * 4 + q) * 16;
      asm volatile("global_load_dwordx4 %0, %1, off sc0 sc1"
                   : "=v"(hv[s]) : "v"(p) : "memory");
    }
    asm volatile("s_waitcnt vmcnt(0)" ::: "memory");
    __builtin_amdgcn_sched_barrier(0);   // rule #18: ds_write below the drain
#pragma unroll
    for (int s = 0; s < 4; ++s) {
      int g0 = wave * 16 + s * 4 + q;
      *(int4v*)((char*)lrow + ((g0 ^ swz) << 4)) = hv[s];
    }
    __syncthreads();   // all waves' ds_writes visible

    // ---- MFMA: A fragments from swizzled LDS
    f32x4 acc[4] = {};
#pragma unroll
    for (int kk = 0; kk < 16; ++kk) {
      int g0 = (kk * 4 + q) ^ swz;
      short8 af = *(const short8*)(lrow + (g0 << 4));
#pragma unroll
      for (int gg = 0; gg < 4; ++gg)
        acc[gg] = __builtin_amdgcn_mfma_f32_16x16x32_bf16(af, bw[kk][gg], acc[gg], 0, 0, 0);
    }

    // ---- epilogue: gates, state update. xp(g,i) from xw0/xw1.
    float hnv[4], cnv[4];
#pragma unroll
    for (int i = 0; i < 4; ++i) {
      float pv[4];
#pragma unroll
      for (int g = 0; g < 4; ++g) {
        int idx = g * 4 + i, wd = idx >> 1;
        unsigned v = (unsigned)(wd < 4 ? xw0[wd] : xw1[wd - 4]);
        unsigned u = (idx & 1) ? (v >> 16) : (v & 0xffffu);
        pv[g] = acc[g][i] + bf2f(u);
      }
      float fg = sigf(pv[0]), ig = sigf(pv[1]), gg2 = tanh_fast(pv[2]), og = sigf(pv[3]);
      float cn = fg * c_state[i] + ig * gg2;
      c_state[i] = cn;
      cnv[i] = cn;
      hnv[i] = og * tanh_fast(cn);
    }
    // ---- h stores -> drain -> flag publish (R10-proven); out stores AFTER
    char* hnxt = (char*)hbuf + (cur ^ 1) * (BATCH * HDIM * 2) +
                 ((size_t)(w * 16 + mrow) * 512 + hc0 + col) * 2;
#pragma unroll
    for (int i = 0; i < 4; ++i) {
      unsigned hb16 = bfbits(hnv[i]);
      void* p = hnxt + i * 1024;
      asm volatile("global_store_short %0, %1, off sc0 sc1"
                   :: "v"(p), "v"(hb16) : "memory");
    }
    asm volatile("s_waitcnt vmcnt(0)" ::: "memory");  // h stores at LLC
    if (t < T_STEPS - 1 && lane == 0) {
      int nv = t + 1;
      int* fp2 = flags + w * 32 + j;
      asm volatile("global_store_dword %0, %1, off sc0 sc1"
                   :: "v"(fp2), "v"(nv) : "memory");
    }
    float* outb = out + ((size_t)t * BATCH + w * 16 + mrow) * HDIM + hc0 + col;
#pragma unroll
    for (int i = 0; i < 4; ++i) outb[(size_t)i * HDIM] = hnv[i];
    if (t == T_STEPS - 1) {
#pragma unroll
      for (int i = 0; i < 4; ++i) {
        out_hx[(size_t)(w * 16 + mrow + i) * HDIM + hc0 + col] = hnv[i];
        out_cx[(size_t)(w * 16 + mrow + i) * HDIM + hc0 + col] = cnv[i];
      }
    }
  }
}

extern "C" void kernel_launch(void* const* d_in, const int* in_sizes, int n_in,
                              void* d_out, int out_size, void* d_ws, size_t ws_size,
                              hipStream_t stream) {
  const float* x   = (const float*)d_in[0];
  const float* Wf  = (const float*)d_in[1];
  const float* bf_ = (const float*)d_in[2];
  const float* Wi  = (const float*)d_in[3];
  const float* bi  = (const float*)d_in[4];
  const float* Wg  = (const float*)d_in[5];
  const float* bg  = (const float*)d_in[6];
  const float* Wo  = (const float*)d_in[7];
  const float* bo  = (const float*)d_in[8];

  char* ws = (char*)d_ws;
  __hip_bfloat16* xbf   = (__hip_bfloat16*)(ws);                 // 33,554,432 B
  __hip_bfloat16* wxbt  = (__hip_bfloat16*)(ws + 33554432);      //  2,097,152 B
  __hip_bfloat16* whbt  = (__hip_bfloat16*)(ws + 35651584);      //  2,097,152 B
  float*          bias  = (float*)         (ws + 37748736);      //      8,192 B
  __hip_bfloat16* xproj = (__hip_bfloat16*)(ws + 37756928);      // 134,217,728 B
  __hip_bfloat16* hbuf  = (__hip_bfloat16*)(ws + 171974656);     //    131,072 B
  int*            flags = (int*)           (ws + 172105728);     //        512 B

  k_prep <<<4096, 256, 0, stream>>>(Wf, bf_, Wi, bi, Wg, bg, Wo, bo,
                                    wxbt, whbt, bias, hbuf, flags);
  k_convx<<<8192, 256, 0, stream>>>(x, xbf);
  k_xproj<<<dim3(16, 256), 256, 0, stream>>>(xbf, wxbt, bias, xproj);
  k_recur<<<32, 256, 0, stream>>>(xproj, whbt, hbuf, (float*)d_out, flags);
}

// Round 15
// 1653.841 us; speedup vs baseline: 1.7852x; 1.1936x over previous
//
#include <hip/hip_runtime.h>
#include <hip/hip_bf16.h>
#include <stdint.h>
#include <stddef.h>

// LSTM: T=512, B=64, I=512, H=512.
// Phase 1: xproj GEMM (bf16 MFMA), output in CONSUMER layout (R13-verified):
//   elem = ((((t*32+j)*4+w)*4+q)*16+c)*16 + g*4+i  -> 2 dwordx4 per lane/step.
// Phase 2: 128 independent waves (32 col-groups x 4 row-groups), 64-thr WGs.
//   R15 = R10 champion + pre-issued poll:
//   - after publishing flag(t+1), each lane pre-issues ONE flag load (f0pre);
//     at step t+1's top (after vmcnt(0) for bw/xp) the value is already home:
//     if f0pre >= t, skip the spin entirely (catch cost -> 0). Stale -> R10
//     2-deep spin fallback. Own-flag lanes skip the check (avoids racing the
//     own store).
//   - xp loads: 2x dwordx4 (consumer-layout xproj) instead of 16 ushorts.
//   Producer order unchanged (R9-proven): h-stores -> vmcnt(0) -> flag.

#define T_STEPS 512
#define BATCH   64
#define HDIM    512

using short8 = __attribute__((ext_vector_type(8))) short;  // 8 bf16 (4 VGPR) MFMA operand
using f32x4  = __attribute__((ext_vector_type(4))) float;  // MFMA accumulator
using int4v  = __attribute__((ext_vector_type(4))) int;

__device__ __forceinline__ void gload_lds16(const void* g, void* l) {
  __builtin_amdgcn_global_load_lds((const __attribute__((address_space(1))) void*)g,
                                   (__attribute__((address_space(3))) void*)l, 16, 0, 0);
}
__device__ __forceinline__ float sigf(float x) { return 1.0f / (1.0f + __expf(-x)); }
__device__ __forceinline__ float tanh_fast(float x) {
  x = fminf(fmaxf(x, -15.0f), 15.0f);
  float e = __expf(2.0f * x);
  return (e - 1.0f) / (e + 1.0f);
}
__device__ __forceinline__ short bfb(float f) {
  __hip_bfloat16 h = __float2bfloat16(f);
  short s; __builtin_memcpy(&s, &h, 2); return s;
}
__device__ __forceinline__ unsigned bfbits(float f) {
  __hip_bfloat16 h = __float2bfloat16(f);
  unsigned short s; __builtin_memcpy(&s, &h, 2); return (unsigned)s;
}
__device__ __forceinline__ float bf2f(unsigned u) {  // bf16 bits (low 16) -> f32
  return __builtin_bit_cast(float, u << 16);
}

// ---------------- prep: build Wx_bt/Wh_bt [2048][512] bf16, bias[2048], zero hbuf+flags
__global__ __launch_bounds__(256) void k_prep(
    const float* __restrict__ Wf, const float* __restrict__ bf_,
    const float* __restrict__ Wi, const float* __restrict__ bi,
    const float* __restrict__ Wg, const float* __restrict__ bg,
    const float* __restrict__ Wo, const float* __restrict__ bo,
    __hip_bfloat16* __restrict__ wxbt, __hip_bfloat16* __restrict__ whbt,
    float* __restrict__ bias, __hip_bfloat16* __restrict__ hbuf, int* __restrict__ flags)
{
  int idx = blockIdx.x * 256 + threadIdx.x;   // 4096 blocks -> 1,048,576 = 2048*512
  int row = idx >> 9;                          // 0..2047 (gate-major)
  int k   = idx & 511;
  int g = row >> 9, r = row & 511;
  const float* W = (g == 0) ? Wf : (g == 1) ? Wi : (g == 2) ? Wg : Wo;
  const float* B = (g == 0) ? bf_ : (g == 1) ? bi : (g == 2) ? bg : bo;
  wxbt[(size_t)row * 512 + k] = __float2bfloat16(W[(size_t)r * 1024 + k]);
  whbt[(size_t)row * 512 + k] = __float2bfloat16(W[(size_t)r * 1024 + 512 + k]);
  if (k == 0) bias[row] = B[r];
  if (idx < 2 * BATCH * HDIM) hbuf[idx] = __float2bfloat16(0.0f);  // both h buffers
  if (idx < 128) flags[idx] = 0;
}

// ---------------- convert x to bf16, 8 elems/thread
__global__ __launch_bounds__(256) void k_convx(const float* __restrict__ x,
                                               __hip_bfloat16* __restrict__ xbf)
{
  int idx = blockIdx.x * 256 + threadIdx.x;    // 8192 blocks
  const float4* p = (const float4*)x + (size_t)idx * 2;
  float4 a = p[0], b = p[1];
  short8 o;
  o[0]=bfb(a.x); o[1]=bfb(a.y); o[2]=bfb(a.z); o[3]=bfb(a.w);
  o[4]=bfb(b.x); o[5]=bfb(b.y); o[6]=bfb(b.z); o[7]=bfb(b.w);
  *(short8*)((short*)xbf + (size_t)idx * 8) = o;
}

// ---------------- phase 1 GEMM: [32768,512] x [512 -> 2048] (B^T layout), +bias
// Output layout: elem index = ((((t*32+j)*4+w)*4+q)*16+c)*16 + g*4+i  (R13-verified)
__global__ __launch_bounds__(256) void k_xproj(
    const __hip_bfloat16* __restrict__ xbf,   // [32768][512]
    const __hip_bfloat16* __restrict__ wxbt,  // [2048][512]
    const float* __restrict__ bias,           // [2048]
    __hip_bfloat16* __restrict__ xproj)       // consumer layout, 67,108,864 elems
{
  __shared__ __align__(16) short aT[128 * 64];
  __shared__ __align__(16) short bT[128 * 64];
  const int tid = threadIdx.x, lane = tid & 63, wave = tid >> 6;
  const int m0 = blockIdx.y * 128, n0 = blockIdx.x * 128;
  const int wr = wave >> 1, wc = wave & 1;

  f32x4 acc[4][4] = {};

  for (int s = 0; s < 8; ++s) {               // K=512, BK=64
    __syncthreads();
    const int kbyte = s * 128;
#pragma unroll
    for (int it = 0; it < 4; ++it) {
      int flat = it * 256 + tid;
      int row = flat >> 3, gr = flat & 7;
      int sgr = gr ^ (row & 7);
      const char* ga = (const char*)xbf  + (size_t)(m0 + row) * 1024 + kbyte + sgr * 16;
      const char* gb = (const char*)wxbt + (size_t)(n0 + row) * 1024 + kbyte + sgr * 16;
      gload_lds16(ga, (char*)aT + (it * 256 + wave * 64) * 16);
      gload_lds16(gb, (char*)bT + (it * 256 + wave * 64) * 16);
    }
    __syncthreads();
#pragma unroll
    for (int kk2 = 0; kk2 < 2; ++kk2) {
      short8 af[4], bfr[4];
#pragma unroll
      for (int mt = 0; mt < 4; ++mt) {
        int r = wr * 64 + mt * 16 + (lane & 15);
        int g = (kk2 * 4 + (lane >> 4)) ^ (r & 7);
        af[mt] = *(const short8*)((const char*)aT + r * 128 + g * 16);
      }
#pragma unroll
      for (int nt = 0; nt < 4; ++nt) {
        int r = wc * 64 + nt * 16 + (lane & 15);
        int g = (kk2 * 4 + (lane >> 4)) ^ (r & 7);
        bfr[nt] = *(const short8*)((const char*)bT + r * 128 + g * 16);
      }
#pragma unroll
      for (int mt = 0; mt < 4; ++mt)
#pragma unroll
        for (int nt = 0; nt < 4; ++nt)
          acc[mt][nt] = __builtin_amdgcn_mfma_f32_16x16x32_bf16(af[mt], bfr[nt], acc[mt][nt], 0, 0, 0);
    }
  }
  // epilogue: + bias, scatter into consumer layout (R13-verified mapping).
#pragma unroll
  for (int nt = 0; nt < 4; ++nt) {
    int n = n0 + wc * 64 + nt * 16 + (lane & 15);
    float bv = bias[n];
    int j2 = (n >> 4) & 31, g2 = n >> 9, c2 = n & 15;
#pragma unroll
    for (int mt = 0; mt < 4; ++mt)
#pragma unroll
      for (int i2 = 0; i2 < 4; ++i2) {
        int m = m0 + wr * 64 + mt * 16 + (lane >> 4) * 4 + i2;
        int tt = m >> 6, rr = m & 63;
        int w2 = rr >> 4, q2 = (rr >> 2) & 3, ii = rr & 3;
        size_t off = ((((size_t)tt * 32 + j2) * 4 + w2) * 4 + q2) * 16 + c2;
        xproj[off * 16 + g2 * 4 + ii] = __float2bfloat16(acc[mt][nt][i2] + bv);
      }
  }
}

// ---------------- phase 2: 128 independent waves (64-thread WGs).
// Wave bid: j = bid>>2 owns h-cols [j*16,j*16+16); w = bid&3 owns batch rows
// [w*16,w*16+16). flags[w*32+j]. All cross-wave traffic via sc0 sc1 (LLC).
__global__ __launch_bounds__(64, 1) void k_recur(
    const __hip_bfloat16* __restrict__ xproj, // consumer layout
    const __hip_bfloat16* __restrict__ whbt,  // [2048][512]
    __hip_bfloat16* __restrict__ hbuf,        // [2][64][512]
    float* __restrict__ out,                  // outputs | hx | cx
    int* __restrict__ flags)                  // [128], layout w*32+j
{
  const int lane = threadIdx.x;
  const int bid  = blockIdx.x;                 // 0..127
  const int j = bid >> 2, w = bid & 3;
  const int hc0 = j * 16, col = lane & 15, q = lane >> 4, mrow = q * 4;
  const bool need = (lane & 31) != j;          // own flag is true by construction

  float c_state[4] = {0.f, 0.f, 0.f, 0.f};
  float* out_hx = out + (size_t)T_STEPS * BATCH * HDIM;
  float* out_cx = out_hx + BATCH * HDIM;

  // invariant base for this wave's Wh slice: B[k][c]=whbt[g*512+hc0+c][k],
  // per lane c=lane&15, k=kk*32+q*8+0..7
  const char* wbase = (const char*)whbt + ((size_t)(hc0 + col)) * 1024 + q * 16;
  const int* fp = flags + w * 32 + (lane & 31);

  int f0pre = 0;                               // pre-issued poll value

  for (int t = 0; t < T_STEPS; ++t) {
    const int cur = t & 1;
    // ---- Wh slice loads: plain, L2-hot, issued first so they fly into the
    // loop-top drain. Pinned here by the asm "memory" clobbers below.
    short8 bw[16][4];
#pragma unroll
    for (int kk = 0; kk < 16; ++kk)
#pragma unroll
      for (int gg = 0; gg < 4; ++gg)
        bw[kk][gg] = *(const short8*)(wbase + (size_t)gg * 524288 + (size_t)kk * 64);

    // ---- xp loads: 2x dwordx4 (consumer layout), plain
    const char* xpb = (const char*)xproj +
        (((((size_t)t * 32 + j) * 4 + w) * 4 + q) * 16 + col) * 32;
    int4v xw0 = *(const int4v*)xpb;
    int4v xw1 = *(const int4v*)(xpb + 16);

    // ---- drain everything (bw, xp, prior f0pre/flag/out-stores); then check
    // the pre-issued poll. Usually f0pre >= t -> no spin at all.
    asm volatile("s_waitcnt vmcnt(0)" ::: "memory");
    __builtin_amdgcn_sched_barrier(0);
    if (t > 0 && need && f0pre < t) {
      // fallback: R10-proven 2-deep pipelined spin (participating lanes only)
      int f0, f1;
      asm volatile("global_load_dword %0, %1, off sc0 sc1" : "=v"(f0) : "v"(fp) : "memory");
      asm volatile("s_waitcnt vmcnt(0)" ::: "memory");
      if (f0 < t) {
        for (;;) {
          asm volatile("global_load_dword %0, %1, off sc0 sc1" : "=v"(f1) : "v"(fp) : "memory");
          asm volatile("s_waitcnt vmcnt(1)" ::: "memory");   // f0 complete
          if (f0 >= t) break;                                 // f1 still flying
          asm volatile("global_load_dword %0, %1, off sc0 sc1" : "=v"(f0) : "v"(fp) : "memory");
          asm volatile("s_waitcnt vmcnt(1)" ::: "memory");   // f1 complete
          if (f1 >= t) break;                                 // f0 still flying
        }
        asm volatile("s_waitcnt vmcnt(0)" ::: "memory");      // retire leftover poll
      }
    }
    __builtin_amdgcn_sched_barrier(0);

    // ---- issue all 16 h-chunk loads (FIFO is empty here), consume with
    // counted vmcnt (R10-proven exact).
    const char* hb = (const char*)hbuf + cur * (BATCH * HDIM * 2) +
                     (size_t)(w * 16 + (lane & 15)) * 1024 + q * 16;
    int4v araw[16];
#pragma unroll
    for (int kk = 0; kk < 16; ++kk) {
      const void* p = hb + kk * 64;
      asm volatile("global_load_dwordx4 %0, %1, off sc0 sc1"
                   : "=v"(araw[kk]) : "v"(p) : "memory");
    }
    f32x4 acc[4] = {};
#pragma unroll
    for (int kk = 0; kk < 16; ++kk) {
      asm volatile("s_waitcnt vmcnt(%0)" :: "i"(15 - kk) : "memory");  // chunk kk landed
      __builtin_amdgcn_sched_barrier(0);   // rule #18: MFMA stays below its wait
      short8 af = __builtin_bit_cast(short8, araw[kk]);
#pragma unroll
      for (int gg = 0; gg < 4; ++gg)
        acc[gg] = __builtin_amdgcn_mfma_f32_16x16x32_bf16(af, bw[kk][gg], acc[gg], 0, 0, 0);
    }

    // ---- epilogue: gates, state update. xp(g,i) from xw0/xw1 (R13-verified).
    float hnv[4], cnv[4];
#pragma unroll
    for (int i = 0; i < 4; ++i) {
      float pv[4];
#pragma unroll
      for (int g = 0; g < 4; ++g) {
        int idx = g * 4 + i, wd = idx >> 1;
        unsigned v = (unsigned)(wd < 4 ? xw0[wd] : xw1[wd - 4]);
        unsigned u = (idx & 1) ? (v >> 16) : (v & 0xffffu);
        pv[g] = acc[g][i] + bf2f(u);
      }
      float fg = sigf(pv[0]), ig = sigf(pv[1]), gg2 = tanh_fast(pv[2]), og = sigf(pv[3]);
      float cn = fg * c_state[i] + ig * gg2;
      c_state[i] = cn;
      cnv[i] = cn;
      hnv[i] = og * tanh_fast(cn);
    }
    // ---- h stores -> drain -> flag publish -> PRE-ISSUE next poll;
    // out stores AFTER (drained at next loop top).
    char* hnxt = (char*)hbuf + (cur ^ 1) * (BATCH * HDIM * 2) +
                 ((size_t)(w * 16 + mrow) * 512 + hc0 + col) * 2;
#pragma unroll
    for (int i = 0; i < 4; ++i) {
      unsigned hb16 = bfbits(hnv[i]);
      void* p = hnxt + i * 1024;
      asm volatile("global_store_short %0, %1, off sc0 sc1"
                   :: "v"(p), "v"(hb16) : "memory");
    }
    asm volatile("s_waitcnt vmcnt(0)" ::: "memory");  // h stores at LLC
    if (t < T_STEPS - 1) {
      if (lane == 0) {
        int nv = t + 1;
        int* fp2 = flags + w * 32 + j;
        asm volatile("global_store_dword %0, %1, off sc0 sc1"
                     :: "v"(fp2), "v"(nv) : "memory");
      }
      // pre-issue next step's poll (value checked after next loop-top drain)
      asm volatile("global_load_dword %0, %1, off sc0 sc1"
                   : "=v"(f0pre) : "v"(fp) : "memory");
    }
    float* outb = out + ((size_t)t * BATCH + w * 16 + mrow) * HDIM + hc0 + col;
#pragma unroll
    for (int i = 0; i < 4; ++i) outb[(size_t)i * HDIM] = hnv[i];
    if (t == T_STEPS - 1) {
#pragma unroll
      for (int i = 0; i < 4; ++i) {
        out_hx[(size_t)(w * 16 + mrow + i) * HDIM + hc0 + col] = hnv[i];
        out_cx[(size_t)(w * 16 + mrow + i) * HDIM + hc0 + col] = cnv[i];
      }
    }
  }
}

extern "C" void kernel_launch(void* const* d_in, const int* in_sizes, int n_in,
                              void* d_out, int out_size, void* d_ws, size_t ws_size,
                              hipStream_t stream) {
  const float* x   = (const float*)d_in[0];
  const float* Wf  = (const float*)d_in[1];
  const float* bf_ = (const float*)d_in[2];
  const float* Wi  = (const float*)d_in[3];
  const float* bi  = (const float*)d_in[4];
  const float* Wg  = (const float*)d_in[5];
  const float* bg  = (const float*)d_in[6];
  const float* Wo  = (const float*)d_in[7];
  const float* bo  = (const float*)d_in[8];

  char* ws = (char*)d_ws;
  __hip_bfloat16* xbf   = (__hip_bfloat16*)(ws);                 // 33,554,432 B
  __hip_bfloat16* wxbt  = (__hip_bfloat16*)(ws + 33554432);      //  2,097,152 B
  __hip_bfloat16* whbt  = (__hip_bfloat16*)(ws + 35651584);      //  2,097,152 B
  float*          bias  = (float*)         (ws + 37748736);      //      8,192 B
  __hip_bfloat16* xproj = (__hip_bfloat16*)(ws + 37756928);      // 134,217,728 B
  __hip_bfloat16* hbuf  = (__hip_bfloat16*)(ws + 171974656);     //    131,072 B
  int*            flags = (int*)           (ws + 172105728);     //        512 B

  k_prep <<<4096, 256, 0, stream>>>(Wf, bf_, Wi, bi, Wg, bg, Wo, bo,
                                    wxbt, whbt, bias, hbuf, flags);
  k_convx<<<8192, 256, 0, stream>>>(x, xbf);
  k_xproj<<<dim3(16, 256), 256, 0, stream>>>(xbf, wxbt, bias, xproj);
  k_recur<<<128, 64, 0, stream>>>(xproj, whbt, hbuf, (float*)d_out, flags);
}

// Round 17
// 1614.875 us; speedup vs baseline: 1.8282x; 1.0241x over previous
//
#include <hip/hip_runtime.h>
#include <hip/hip_bf16.h>
#include <stdint.h>
#include <stddef.h>

// LSTM: T=512, B=64, I=512, H=512.
// Phase 1: xproj GEMM (bf16 MFMA), output in CONSUMER layout (R13/R15-verified):
//   elem = ((((t*32+j)*4+w)*4+q)*16+c)*16 + g*4+i  -> 2 dwordx4 per lane/step.
// Phase 2: 128 independent waves (32 col-groups x 4 row-groups), 64-thr WGs.
//   R17 = R16 intent with the LDS address bug fixed:
//   - Wh staged ONCE into LDS (64 KB, phys granule = logical ^ (row&7),
//     rule-21 staging: linear dest + pre-swizzled per-lane global source);
//     per-step reads via lgkmcnt (OFF the vmcnt path), pipelined 2 chunks
//     ahead under the MFMA consume.
//     READ FIX: byte = gg*16384 + col*1024 + (((kk*4+q) ^ (col&7)) << 4)
//     (R16 split the XOR from q -> carry corruption, absmax 0.152).
//   - per-step vmcnt FIFO = h-loads only -> counted consume exact; loop-top
//     drain covers just the 2 carried xp loads.
//   - producer side: R10-proven verbatim (h-stores -> vmcnt(0) -> flag, all
//     with "memory" clobbers); out stores + next-step xp after the flag.

#define T_STEPS 512
#define BATCH   64
#define HDIM    512

using short8 = __attribute__((ext_vector_type(8))) short;  // 8 bf16 (4 VGPR) MFMA operand
using f32x4  = __attribute__((ext_vector_type(4))) float;  // MFMA accumulator
using int4v  = __attribute__((ext_vector_type(4))) int;

__device__ __forceinline__ void gload_lds16(const void* g, void* l) {
  __builtin_amdgcn_global_load_lds((const __attribute__((address_space(1))) void*)g,
                                   (__attribute__((address_space(3))) void*)l, 16, 0, 0);
}
__device__ __forceinline__ float sigf(float x) { return 1.0f / (1.0f + __expf(-x)); }
__device__ __forceinline__ float tanh_fast(float x) {
  x = fminf(fmaxf(x, -15.0f), 15.0f);
  float e = __expf(2.0f * x);
  return (e - 1.0f) / (e + 1.0f);
}
__device__ __forceinline__ short bfb(float f) {
  __hip_bfloat16 h = __float2bfloat16(f);
  short s; __builtin_memcpy(&s, &h, 2); return s;
}
__device__ __forceinline__ unsigned bfbits(float f) {
  __hip_bfloat16 h = __float2bfloat16(f);
  unsigned short s; __builtin_memcpy(&s, &h, 2); return (unsigned)s;
}
__device__ __forceinline__ float bf2f(unsigned u) {  // bf16 bits (low 16) -> f32
  return __builtin_bit_cast(float, u << 16);
}

// ---------------- prep: build Wx_bt/Wh_bt [2048][512] bf16, bias[2048], zero hbuf+flags
__global__ __launch_bounds__(256) void k_prep(
    const float* __restrict__ Wf, const float* __restrict__ bf_,
    const float* __restrict__ Wi, const float* __restrict__ bi,
    const float* __restrict__ Wg, const float* __restrict__ bg,
    const float* __restrict__ Wo, const float* __restrict__ bo,
    __hip_bfloat16* __restrict__ wxbt, __hip_bfloat16* __restrict__ whbt,
    float* __restrict__ bias, __hip_bfloat16* __restrict__ hbuf, int* __restrict__ flags)
{
  int idx = blockIdx.x * 256 + threadIdx.x;   // 4096 blocks -> 1,048,576 = 2048*512
  int row = idx >> 9;                          // 0..2047 (gate-major)
  int k   = idx & 511;
  int g = row >> 9, r = row & 511;
  const float* W = (g == 0) ? Wf : (g == 1) ? Wi : (g == 2) ? Wg : Wo;
  const float* B = (g == 0) ? bf_ : (g == 1) ? bi : (g == 2) ? bg : bo;
  wxbt[(size_t)row * 512 + k] = __float2bfloat16(W[(size_t)r * 1024 + k]);
  whbt[(size_t)row * 512 + k] = __float2bfloat16(W[(size_t)r * 1024 + 512 + k]);
  if (k == 0) bias[row] = B[r];
  if (idx < 2 * BATCH * HDIM) hbuf[idx] = __float2bfloat16(0.0f);  // both h buffers
  if (idx < 128) flags[idx] = 0;
}

// ---------------- convert x to bf16, 8 elems/thread
__global__ __launch_bounds__(256) void k_convx(const float* __restrict__ x,
                                               __hip_bfloat16* __restrict__ xbf)
{
  int idx = blockIdx.x * 256 + threadIdx.x;    // 8192 blocks
  const float4* p = (const float4*)x + (size_t)idx * 2;
  float4 a = p[0], b = p[1];
  short8 o;
  o[0]=bfb(a.x); o[1]=bfb(a.y); o[2]=bfb(a.z); o[3]=bfb(a.w);
  o[4]=bfb(b.x); o[5]=bfb(b.y); o[6]=bfb(b.z); o[7]=bfb(b.w);
  *(short8*)((short*)xbf + (size_t)idx * 8) = o;
}

// ---------------- phase 1 GEMM: [32768,512] x [512 -> 2048] (B^T layout), +bias
// Output layout: elem index = ((((t*32+j)*4+w)*4+q)*16+c)*16 + g*4+i  (R13-verified)
__global__ __launch_bounds__(256) void k_xproj(
    const __hip_bfloat16* __restrict__ xbf,   // [32768][512]
    const __hip_bfloat16* __restrict__ wxbt,  // [2048][512]
    const float* __restrict__ bias,           // [2048]
    __hip_bfloat16* __restrict__ xproj)       // consumer layout, 67,108,864 elems
{
  __shared__ __align__(16) short aT[128 * 64];
  __shared__ __align__(16) short bT[128 * 64];
  const int tid = threadIdx.x, lane = tid & 63, wave = tid >> 6;
  const int m0 = blockIdx.y * 128, n0 = blockIdx.x * 128;
  const int wr = wave >> 1, wc = wave & 1;

  f32x4 acc[4][4] = {};

  for (int s = 0; s < 8; ++s) {               // K=512, BK=64
    __syncthreads();
    const int kbyte = s * 128;
#pragma unroll
    for (int it = 0; it < 4; ++it) {
      int flat = it * 256 + tid;
      int row = flat >> 3, gr = flat & 7;
      int sgr = gr ^ (row & 7);
      const char* ga = (const char*)xbf  + (size_t)(m0 + row) * 1024 + kbyte + sgr * 16;
      const char* gb = (const char*)wxbt + (size_t)(n0 + row) * 1024 + kbyte + sgr * 16;
      gload_lds16(ga, (char*)aT + (it * 256 + wave * 64) * 16);
      gload_lds16(gb, (char*)bT + (it * 256 + wave * 64) * 16);
    }
    __syncthreads();
#pragma unroll
    for (int kk2 = 0; kk2 < 2; ++kk2) {
      short8 af[4], bfr[4];
#pragma unroll
      for (int mt = 0; mt < 4; ++mt) {
        int r = wr * 64 + mt * 16 + (lane & 15);
        int g = (kk2 * 4 + (lane >> 4)) ^ (r & 7);
        af[mt] = *(const short8*)((const char*)aT + r * 128 + g * 16);
      }
#pragma unroll
      for (int nt = 0; nt < 4; ++nt) {
        int r = wc * 64 + nt * 16 + (lane & 15);
        int g = (kk2 * 4 + (lane >> 4)) ^ (r & 7);
        bfr[nt] = *(const short8*)((const char*)bT + r * 128 + g * 16);
      }
#pragma unroll
      for (int mt = 0; mt < 4; ++mt)
#pragma unroll
        for (int nt = 0; nt < 4; ++nt)
          acc[mt][nt] = __builtin_amdgcn_mfma_f32_16x16x32_bf16(af[mt], bfr[nt], acc[mt][nt], 0, 0, 0);
    }
  }
  // epilogue: + bias, scatter into consumer layout (R13-verified mapping).
#pragma unroll
  for (int nt = 0; nt < 4; ++nt) {
    int n = n0 + wc * 64 + nt * 16 + (lane & 15);
    float bv = bias[n];
    int j2 = (n >> 4) & 31, g2 = n >> 9, c2 = n & 15;
#pragma unroll
    for (int mt = 0; mt < 4; ++mt)
#pragma unroll
      for (int i2 = 0; i2 < 4; ++i2) {
        int m = m0 + wr * 64 + mt * 16 + (lane >> 4) * 4 + i2;
        int tt = m >> 6, rr = m & 63;
        int w2 = rr >> 4, q2 = (rr >> 2) & 3, ii = rr & 3;
        size_t off = ((((size_t)tt * 32 + j2) * 4 + w2) * 4 + q2) * 16 + c2;
        xproj[off * 16 + g2 * 4 + ii] = __float2bfloat16(acc[mt][nt][i2] + bv);
      }
  }
}

// ---------------- phase 2: 128 independent waves (64-thread WGs).
// Wave bid: j = bid>>2 owns h-cols [j*16,j*16+16); w = bid&3 owns batch rows
// [w*16,w*16+16). flags[w*32+j]. Cross-wave traffic via sc0 sc1 (LLC).
__global__ __launch_bounds__(64, 1) void k_recur(
    const __hip_bfloat16* __restrict__ xproj, // consumer layout
    const __hip_bfloat16* __restrict__ whbt,  // [2048][512]
    __hip_bfloat16* __restrict__ hbuf,        // [2][64][512]
    float* __restrict__ out,                  // outputs | hx | cx
    int* __restrict__ flags)                  // [128], layout w*32+j
{
  __shared__ __align__(16) short wlds[64 * 512];   // 64 KB: row = g*16+c, swizzled
  const int lane = threadIdx.x;
  const int bid  = blockIdx.x;                 // 0..127
  const int j = bid >> 2, w = bid & 3;
  const int hc0 = j * 16, col = lane & 15, q = lane >> 4, mrow = q * 4;

  // ---- stage Wh into LDS ONCE. rule 21: linear dest (row it, lane granule),
  // pre-swizzled per-lane global source (granule lane ^ (it&7)).
  // LDS[r][p] = W_r[p ^ (r&7)]; note (g*16+c)&7 == c&7.
  for (int it = 0; it < 64; ++it) {
    int sgr = lane ^ (it & 7);
    const char* gsrc = (const char*)whbt +
        ((size_t)((it >> 4) * 512 + hc0 + (it & 15))) * 1024 + sgr * 16;
    gload_lds16(gsrc, (char*)wlds + it * 1024);   // uniform base; HW adds lane*16
  }
  asm volatile("s_waitcnt vmcnt(0)" ::: "memory");
  __builtin_amdgcn_sched_barrier(0);           // no LDS read above the staging drain

  float c_state[4] = {0.f, 0.f, 0.f, 0.f};
  float* out_hx = out + (size_t)T_STEPS * BATCH * HDIM;
  float* out_cx = out_hx + BATCH * HDIM;

  const int* fp = flags + w * 32 + (lane & 31);
  // per-lane LDS row base (row = gg*16 + col)
  const char* lbase = (const char*)wlds + (size_t)col * 1024;
  const int   swl   = col & 7;

  // xp for t=0 (carried plain loads; drained by the t=0 vmcnt(0))
  const char* xpb0 = (const char*)xproj +
      ((((size_t)0 * 32 + j) * 4 + w) * 4 + q) * 512 + (size_t)col * 32;
  int4v xw0c = *(const int4v*)xpb0;
  int4v xw1c = *(const int4v*)(xpb0 + 16);

  for (int t = 0; t < T_STEPS; ++t) {
    const int cur = t & 1;
    // ---- 2-deep pipelined spin (R10-proven). First vmcnt(0) drains the
    // carried xp loads + last iteration's out stores too.
    if (t > 0) {
      int f0, f1;
      asm volatile("global_load_dword %0, %1, off sc0 sc1" : "=v"(f0) : "v"(fp) : "memory");
      asm volatile("s_waitcnt vmcnt(0)" ::: "memory");
      if (f0 < t) {
        for (;;) {
          asm volatile("global_load_dword %0, %1, off sc0 sc1" : "=v"(f1) : "v"(fp) : "memory");
          asm volatile("s_waitcnt vmcnt(1)" ::: "memory");   // f0 complete
          if (f0 >= t) break;                                 // f1 still flying
          asm volatile("global_load_dword %0, %1, off sc0 sc1" : "=v"(f0) : "v"(fp) : "memory");
          asm volatile("s_waitcnt vmcnt(1)" ::: "memory");   // f1 complete
          if (f1 >= t) break;                                 // f0 still flying
        }
        asm volatile("s_waitcnt vmcnt(0)" ::: "memory");      // retire leftover poll
      }
    } else {
      asm volatile("s_waitcnt vmcnt(0)" ::: "memory");        // t=0: drain xp
    }
    __builtin_amdgcn_sched_barrier(0);

    // ---- issue all 16 h-chunk loads (vmcnt FIFO = h only), consume with
    // counted vmcnt; Wh from LDS pipelined 2 chunks ahead (lgkmcnt path).
    const char* hb = (const char*)hbuf + cur * (BATCH * HDIM * 2) +
                     (size_t)(w * 16 + (lane & 15)) * 1024 + q * 16;
    int4v araw[16];
#pragma unroll
    for (int kk = 0; kk < 16; ++kk) {
      const void* p = hb + kk * 64;
      asm volatile("global_load_dwordx4 %0, %1, off sc0 sc1"
                   : "=v"(araw[kk]) : "v"(p) : "memory");
    }
    short8 bwreg[3][4];
#pragma unroll
    for (int gg = 0; gg < 4; ++gg) {           // preload chunks 0,1
      bwreg[0][gg] = *(const short8*)(lbase + gg * 16384 + ((((0) * 4 + q) ^ swl) << 4));
      bwreg[1][gg] = *(const short8*)(lbase + gg * 16384 + ((((1) * 4 + q) ^ swl) << 4));
    }
    f32x4 acc[4] = {};
#pragma unroll
    for (int kk = 0; kk < 16; ++kk) {
      asm volatile("s_waitcnt vmcnt(%0)" :: "i"(15 - kk) : "memory");  // chunk kk landed
      __builtin_amdgcn_sched_barrier(0);       // rule #18: MFMA below its wait
      if (kk + 2 < 16) {
#pragma unroll
        for (int gg = 0; gg < 4; ++gg)
          bwreg[(kk + 2) % 3][gg] = *(const short8*)(
              lbase + gg * 16384 + ((((kk + 2) * 4 + q) ^ swl) << 4));
      }
      short8 af = __builtin_bit_cast(short8, araw[kk]);
#pragma unroll
      for (int gg = 0; gg < 4; ++gg)
        acc[gg] = __builtin_amdgcn_mfma_f32_16x16x32_bf16(af, bwreg[kk % 3][gg], acc[gg], 0, 0, 0);
    }

    // ---- epilogue: gates, state update. xp(g,i) from carried xw0c/xw1c.
    float hnv[4], cnv[4];
#pragma unroll
    for (int i = 0; i < 4; ++i) {
      float pv[4];
#pragma unroll
      for (int g = 0; g < 4; ++g) {
        int idx = g * 4 + i, wd = idx >> 1;
        unsigned v = (unsigned)(wd < 4 ? xw0c[wd] : xw1c[wd - 4]);
        unsigned u = (idx & 1) ? (v >> 16) : (v & 0xffffu);
        pv[g] = acc[g][i] + bf2f(u);
      }
      float fg = sigf(pv[0]), ig = sigf(pv[1]), gg2 = tanh_fast(pv[2]), og = sigf(pv[3]);
      float cn = fg * c_state[i] + ig * gg2;
      c_state[i] = cn;
      cnv[i] = cn;
      hnv[i] = og * tanh_fast(cn);
    }
    // ---- h stores -> drain -> flag publish (R10-proven verbatim);
    // out stores + next-step xp AFTER (drained at next loop top).
    char* hnxt = (char*)hbuf + (cur ^ 1) * (BATCH * HDIM * 2) +
                 ((size_t)(w * 16 + mrow) * 512 + hc0 + col) * 2;
#pragma unroll
    for (int i = 0; i < 4; ++i) {
      unsigned hb16 = bfbits(hnv[i]);
      void* p = hnxt + i * 1024;
      asm volatile("global_store_short %0, %1, off sc0 sc1"
                   :: "v"(p), "v"(hb16) : "memory");
    }
    asm volatile("s_waitcnt vmcnt(0)" ::: "memory");  // h stores at LLC
    if (t < T_STEPS - 1 && lane == 0) {
      int nv = t + 1;
      int* fp2 = flags + w * 32 + j;
      asm volatile("global_store_dword %0, %1, off sc0 sc1"
                   :: "v"(fp2), "v"(nv) : "memory");
    }
    // ---- carry next step's xp (plain loads; drained by next spin vmcnt(0))
    {
      int tn = (t + 1) & 511;
      const char* xpn = (const char*)xproj +
          ((((size_t)tn * 32 + j) * 4 + w) * 4 + q) * 512 + (size_t)col * 32;
      int4v n0v = *(const int4v*)xpn;
      int4v n1v = *(const int4v*)(xpn + 16);
      // out stores (plain; off the publish path)
      float* outb = out + ((size_t)t * BATCH + w * 16 + mrow) * HDIM + hc0 + col;
#pragma unroll
      for (int i = 0; i < 4; ++i) outb[(size_t)i * HDIM] = hnv[i];
      if (t == T_STEPS - 1) {
#pragma unroll
        for (int i = 0; i < 4; ++i) {
          out_hx[(size_t)(w * 16 + mrow + i) * HDIM + hc0 + col] = hnv[i];
          out_cx[(size_t)(w * 16 + mrow + i) * HDIM + hc0 + col] = cnv[i];
        }
      }
      xw0c = n0v; xw1c = n1v;
    }
  }
}

extern "C" void kernel_launch(void* const* d_in, const int* in_sizes, int n_in,
                              void* d_out, int out_size, void* d_ws, size_t ws_size,
                              hipStream_t stream) {
  const float* x   = (const float*)d_in[0];
  const float* Wf  = (const float*)d_in[1];
  const float* bf_ = (const float*)d_in[2];
  const float* Wi  = (const float*)d_in[3];
  const float* bi  = (const float*)d_in[4];
  const float* Wg  = (const float*)d_in[5];
  const float* bg  = (const float*)d_in[6];
  const float* Wo  = (const float*)d_in[7];
  const float* bo  = (const float*)d_in[8];

  char* ws = (char*)d_ws;
  __hip_bfloat16* xbf   = (__hip_bfloat16*)(ws);                 // 33,554,432 B
  __hip_bfloat16* wxbt  = (__hip_bfloat16*)(ws + 33554432);      //  2,097,152 B
  __hip_bfloat16* whbt  = (__hip_bfloat16*)(ws + 35651584);      //  2,097,152 B
  float*          bias  = (float*)         (ws + 37748736);      //      8,192 B
  __hip_bfloat16* xproj = (__hip_bfloat16*)(ws + 37756928);      // 134,217,728 B
  __hip_bfloat16* hbuf  = (__hip_bfloat16*)(ws + 171974656);     //    131,072 B
  int*            flags = (int*)           (ws + 172105728);     //        512 B

  k_prep <<<4096, 256, 0, stream>>>(Wf, bf_, Wi, bi, Wg, bg, Wo, bo,
                                    wxbt, whbt, bias, hbuf, flags);
  k_convx<<<8192, 256, 0, stream>>>(x, xbf);
  k_xproj<<<dim3(16, 256), 256, 0, stream>>>(xbf, wxbt, bias, xproj);
  k_recur<<<128, 64, 0, stream>>>(xproj, whbt, hbuf, (float*)d_out, flags);
}